// Round 2
// baseline (9238.713 us; speedup 1.0000x reference)
//
#include <hip/hip_runtime.h>
#include <math.h>

namespace {

constexpr int kB = 512;
constexpr int kL = 128;
constexpr int kD = 128;
constexpr int kSteps = 126;   // L - 2

// ---- workspace layout (float offsets) ----
constexpr size_t OFF_W2   = 0;                       // [64][512][2] w_ih pairs: W2[k2][g][k&1]
constexpr size_t OFF_BIAS = 65536;                   // [512] b_ih + b_hh
constexpr size_t OFF_WQTG = 66048;                   // [128][128] wq_g^T
constexpr size_t OFF_WQTP = 82432;                   // wq_p^T
constexpr size_t OFF_WRTG = 98816;                   // wr_g^T
constexpr size_t OFF_WRTP = 115200;                  // wr_p^T
constexpr size_t OFF_REFG = 131584;                  // [L][B][D]
constexpr size_t OFF_REFP = OFF_REFG + (size_t)kL * kB * kD;

constexpr size_t OUT_IDX_OFF = (size_t)kSteps * kB * kL;  // probs first, then idx

// ---- dynamic LDS layout for decode_main (float offsets) ----
constexpr int SM_XH   = 0;       // [256][2]  k-major, bb inner (x in k<128, h in k>=128)
constexpr int SM_C    = 512;     // [2][128]
constexpr int SM_GATES= 768;     // [2][512]
constexpr int SM_RED  = 1792;    // [1024] reduction scratch
constexpr int SM_Q    = 2816;    // [2][128]
constexpr int SM_U    = 3072;    // [2][128]
constexpr int SM_P    = 3328;    // [2][128]
constexpr int SM_GV   = 3584;    // [128][2] interleaved glimpse vector
constexpr int SM_MASK = 3840;    // [2][128]
constexpr int SM_VG   = 4096;    // [128]
constexpr int SM_VP   = 4224;
constexpr int SM_BQG  = 4352;
constexpr int SM_BQP  = 4480;
constexpr int SM_IDX  = 4608;    // 2 ints
constexpr int SM_TOTAL= 4612;

// fast transcendentals: v_exp_f32-based, ~2 ulp, branch-free, inf-safe
__device__ __forceinline__ float tanh_fast(float x) {
  // tanh(x) = 1 - 2/(exp(2x)+1); x->+inf: e=inf -> 1; x->-inf: e=0 -> -1
  return 1.0f - __fdividef(2.0f, __expf(2.0f * x) + 1.0f);
}
__device__ __forceinline__ float sig_fast(float x) {
  return __fdividef(1.0f, 1.0f + __expf(-x));
}

} // namespace

// ---------- one-time: transposed weights + fused bias ----------
extern "C" __global__ void prep_weights(
    const float* __restrict__ w_ih, const float* __restrict__ w_hh,
    const float* __restrict__ b_ih, const float* __restrict__ b_hh,
    const float* __restrict__ wq_p, const float* __restrict__ wq_g,
    const float* __restrict__ wr_p, const float* __restrict__ wr_g,
    float* __restrict__ ws) {
  const int tid = blockIdx.x * blockDim.x + threadIdx.x;
  const int nth = gridDim.x * blockDim.x;
  for (int i = tid; i < 64 * 512 * 2; i += nth) {
    const int k2 = i >> 10, rem = i & 1023, g = rem >> 1, half = rem & 1;
    const int k = k2 * 2 + half;
    ws[OFF_W2 + i] = w_ih[g * 128 + k];
  }
  for (int i = tid; i < 512; i += nth) ws[OFF_BIAS + i] = b_ih[i] + b_hh[i];
  for (int i = tid; i < 128 * 128; i += nth) {
    const int k = i >> 7, j = i & 127;
    ws[OFF_WQTG + i] = wq_g[j * 128 + k];
    ws[OFF_WQTP + i] = wq_p[j * 128 + k];
    ws[OFF_WRTG + i] = wr_g[j * 128 + k];
    ws[OFF_WRTP + i] = wr_p[j * 128 + k];
  }
}

// ---------- one-time: ref_p/ref_g = enc @ wr^T + br (1x1 conv hoisted) ----------
extern "C" __global__ __launch_bounds__(256) void prep_refs(
    const float* __restrict__ enc,
    const float* __restrict__ br_p, const float* __restrict__ br_g,
    float* __restrict__ ws) {
  extern __shared__ float lds[];
  float* s_wrTg = lds;             // 16384
  float* s_wrTp = lds + 16384;     // 16384
  float* s_enc  = lds + 32768;     // [2][128]
  float* ref_g = ws + OFF_REFG;
  float* ref_p = ws + OFF_REFP;
  const int t = threadIdx.x;
  for (int i = t; i < 16384; i += 256) {
    s_wrTg[i] = ws[OFF_WRTG + i];
    s_wrTp[i] = ws[OFF_WRTP + i];
  }
  __syncthreads();
  const int half = t >> 7, j = t & 127;
  const float brg = br_g[j], brp = br_p[j];
  const size_t base = (size_t)blockIdx.x * 64;
  for (int rr = 0; rr < 64; rr += 2) {
    const size_t rid = base + rr + half;   // rid = l*B + b
    s_enc[half * 128 + j] = enc[rid * 128 + j];
    __syncthreads();
    float ag = brg, ap = brp;
    #pragma unroll 8
    for (int k = 0; k < 128; ++k) {
      const float e = s_enc[half * 128 + k];
      ag += e * s_wrTg[k * 128 + j];
      ap += e * s_wrTp[k * 128 + j];
    }
    ref_g[rid * 128 + j] = ag;
    ref_p[rid * 128 + j] = ap;
    __syncthreads();
  }
}

// ---------- persistent decode: one block per 2 batch elements ----------
extern "C" __global__ __launch_bounds__(512) void decode_main(
    const float* __restrict__ dec0, const float* __restrict__ emb,
    const float* __restrict__ h0,   const float* __restrict__ c0,
    const float* __restrict__ enc,  const float* __restrict__ w_hh,
    const float* __restrict__ bq_p, const float* __restrict__ v_p,
    const float* __restrict__ bq_g, const float* __restrict__ v_g,
    const float* __restrict__ ws, float* __restrict__ out) {
  extern __shared__ float sm[];
  int* s_idx = (int*)(sm + SM_IDX);
  const float* W2    = ws + OFF_W2;
  const float* wqTg  = ws + OFF_WQTG;
  const float* wqTp  = ws + OFF_WQTP;
  const float* ref_g = ws + OFF_REFG;
  const float* ref_p = ws + OFF_REFP;

  const int t  = threadIdx.x;
  const int b0 = blockIdx.x * 2;

  // w_hh row for my gate, register-resident across all 126 steps
  float whh[128];
  {
    const float* wr = w_hh + (size_t)t * 128;
    #pragma unroll
    for (int q = 0; q < 32; ++q) {
      const float4 v = *(const float4*)(wr + q * 4);
      whh[q * 4 + 0] = v.x; whh[q * 4 + 1] = v.y;
      whh[q * 4 + 2] = v.z; whh[q * 4 + 3] = v.w;
    }
  }
  const float bias_g = ws[OFF_BIAS + t];

  // one-time LDS fills
  if (t < 128) {
    sm[SM_VG  + t] = v_g[t];
    sm[SM_VP  + t] = v_p[t];
    sm[SM_BQG + t] = bq_g[t];
    sm[SM_BQP + t] = bq_p[t];
  }
  if (t < 256) {
    const int bb = t >> 7, d = t & 127, b = b0 + bb;
    sm[SM_XH + d * 2 + bb]         = dec0[b * 128 + d];   // x part
    sm[SM_XH + (128 + d) * 2 + bb] = h0[b * 128 + d];     // h part
    sm[SM_C + bb * 128 + d]        = c0[b * 128 + d];
    sm[SM_MASK + bb * 128 + d]     = (d < 2) ? 1.f : 0.f; // indices 0,1 pre-visited
  }
  __syncthreads();

  for (int step = 0; step < kSteps; ++step) {
    // ---- Phase L1: gates[g] for both batches; x@w_ih streamed, h@w_hh from regs ----
    {
      float a0 = bias_g, a1 = bias_g;
      const float* wp = W2 + 2 * t;
      #pragma unroll 8
      for (int k2 = 0; k2 < 64; ++k2) {
        const float4 xh = *(const float4*)&sm[SM_XH + k2 * 4];  // x[2k2],x[2k2+1] (b0,b1)
        const float2 w  = *(const float2*)(wp + (size_t)k2 * 1024);
        a0 += xh.x * w.x + xh.z * w.y;
        a1 += xh.y * w.x + xh.w * w.y;
      }
      #pragma unroll
      for (int k2 = 0; k2 < 64; ++k2) {
        const float4 hh = *(const float4*)&sm[SM_XH + 256 + k2 * 4];
        a0 += hh.x * whh[2 * k2] + hh.z * whh[2 * k2 + 1];
        a1 += hh.y * whh[2 * k2] + hh.w * whh[2 * k2 + 1];
      }
      sm[SM_GATES + t]       = a0;
      sm[SM_GATES + 512 + t] = a1;
    }
    __syncthreads();
    // ---- Phase L2: LSTM cell elementwise; mask update (use_prev only) ----
    if (t < 256) {
      const int bb = t >> 7, d = t & 127;
      const float gi = sm[SM_GATES + bb * 512 + d];
      const float gf = sm[SM_GATES + bb * 512 + 128 + d];
      const float gg = sm[SM_GATES + bb * 512 + 256 + d];
      const float go = sm[SM_GATES + bb * 512 + 384 + d];
      const float cc = sig_fast(gf) * sm[SM_C + bb * 128 + d] + sig_fast(gi) * tanh_fast(gg);
      const float hh = sig_fast(go) * tanh_fast(cc);
      sm[SM_C + bb * 128 + d] = cc;
      sm[SM_XH + (128 + d) * 2 + bb] = hh;
    }
    if (step > 0 && t < 2) sm[SM_MASK + t * 128 + s_idx[t]] = 1.f;
    __syncthreads();
    // ---- Phase A1: q_g = h @ wq_g^T + bq_g  (thread = (kq, j), both batches) ----
    {
      const int kq = t >> 7, j = t & 127;
      float acc0 = 0.f, acc1 = 0.f;
      #pragma unroll 8
      for (int kk = 0; kk < 32; ++kk) {
        const int k = kq * 32 + kk;
        const float2 h2 = *(const float2*)&sm[SM_XH + (128 + k) * 2];  // broadcast
        const float w = wqTg[k * 128 + j];
        acc0 += h2.x * w; acc1 += h2.y * w;
      }
      sm[SM_RED + kq * 256 + j]       = acc0;
      sm[SM_RED + kq * 256 + 128 + j] = acc1;
    }
    __syncthreads();
    if (t < 256) {
      const int bb = t >> 7, j = t & 127;
      sm[SM_Q + bb * 128 + j] = sm[SM_BQG + j]
          + sm[SM_RED + bb * 128 + j]       + sm[SM_RED + 256 + bb * 128 + j]
          + sm[SM_RED + 512 + bb * 128 + j] + sm[SM_RED + 768 + bb * 128 + j];
    }
    __syncthreads();
    // ---- Phase A2: glimpse scores u_g[l] = v_g . tanh(ref_g + q_g) ----
    {
      const int lane = t & 63, wv = t >> 6;
      const int sub = lane & 15, rr = lane >> 4;
      const float4 va = *(const float4*)&sm[SM_VG + sub * 8];
      const float4 vb = *(const float4*)&sm[SM_VG + sub * 8 + 4];
      #pragma unroll
      for (int bb = 0; bb < 2; ++bb) {
        const float4 qa = *(const float4*)&sm[SM_Q + bb * 128 + sub * 8];
        const float4 qb = *(const float4*)&sm[SM_Q + bb * 128 + sub * 8 + 4];
        #pragma unroll
        for (int it = 0; it < 4; ++it) {
          const int l = it * 32 + wv * 4 + rr;
          const float* rp = ref_g + ((size_t)l * kB + b0 + bb) * kD + sub * 8;
          const float4 ra = *(const float4*)rp;
          const float4 rb = *(const float4*)(rp + 4);
          float s;
          s  = va.x * tanh_fast(ra.x + qa.x);
          s += va.y * tanh_fast(ra.y + qa.y);
          s += va.z * tanh_fast(ra.z + qa.z);
          s += va.w * tanh_fast(ra.w + qa.w);
          s += vb.x * tanh_fast(rb.x + qb.x);
          s += vb.y * tanh_fast(rb.y + qb.y);
          s += vb.z * tanh_fast(rb.z + qb.z);
          s += vb.w * tanh_fast(rb.w + qb.w);
          s += __shfl_xor(s, 1); s += __shfl_xor(s, 2);
          s += __shfl_xor(s, 4); s += __shfl_xor(s, 8);
          if (sub == 0) {
            if (step > 0 && sm[SM_MASK + bb * 128 + l] != 0.f) s = -INFINITY;
            sm[SM_U + bb * 128 + l] = s;
          }
        }
      }
    }
    __syncthreads();
    // ---- Phase A3: glimpse softmax (wave 0 -> b0, wave 1 -> b1) ----
    if (t < 128) {
      const int bb = t >> 6, lane = t & 63;
      const float v0 = sm[SM_U + bb * 128 + lane], v1 = sm[SM_U + bb * 128 + 64 + lane];
      float m = fmaxf(v0, v1);
      #pragma unroll
      for (int off = 1; off < 64; off <<= 1) m = fmaxf(m, __shfl_xor(m, off, 64));
      const float e0 = __expf(v0 - m), e1 = __expf(v1 - m);
      float ssum = e0 + e1;
      #pragma unroll
      for (int off = 1; off < 64; off <<= 1) ssum += __shfl_xor(ssum, off, 64);
      const float inv = __fdividef(1.0f, ssum);
      sm[SM_P + bb * 128 + lane]      = e0 * inv;
      sm[SM_P + bb * 128 + 64 + lane] = e1 * inv;
    }
    __syncthreads();
    // ---- Phase A4: glimpse readout g = p @ enc ----
    {
      const int lh = t >> 8, bb = (t >> 7) & 1, d = t & 127;
      float acc = 0.f;
      #pragma unroll 4
      for (int ll = 0; ll < 64; ++ll) {
        const int l = lh * 64 + ll;
        acc += sm[SM_P + bb * 128 + l] * enc[((size_t)l * kB + b0 + bb) * kD + d];
      }
      sm[SM_RED + (lh * 2 + bb) * 128 + d] = acc;
    }
    __syncthreads();
    if (t < 256) {
      const int bb = t >> 7, d = t & 127;
      sm[SM_GV + d * 2 + bb] = sm[SM_RED + bb * 128 + d] + sm[SM_RED + (2 + bb) * 128 + d];
    }
    __syncthreads();
    // ---- Phase A5: q_p = g @ wq_p^T + bq_p ----
    {
      const int kq = t >> 7, j = t & 127;
      float acc0 = 0.f, acc1 = 0.f;
      #pragma unroll 8
      for (int kk = 0; kk < 32; ++kk) {
        const int k = kq * 32 + kk;
        const float2 g2 = *(const float2*)&sm[SM_GV + k * 2];  // broadcast
        const float w = wqTp[k * 128 + j];
        acc0 += g2.x * w; acc1 += g2.y * w;
      }
      sm[SM_RED + kq * 256 + j]       = acc0;
      sm[SM_RED + kq * 256 + 128 + j] = acc1;
    }
    __syncthreads();
    if (t < 256) {
      const int bb = t >> 7, j = t & 127;
      sm[SM_Q + bb * 128 + j] = sm[SM_BQP + j]
          + sm[SM_RED + bb * 128 + j]       + sm[SM_RED + 256 + bb * 128 + j]
          + sm[SM_RED + 512 + bb * 128 + j] + sm[SM_RED + 768 + bb * 128 + j];
    }
    __syncthreads();
    // ---- Phase A6: pointer scores, clipped 10*tanh(u), masked ----
    {
      const int lane = t & 63, wv = t >> 6;
      const int sub = lane & 15, rr = lane >> 4;
      const float4 va = *(const float4*)&sm[SM_VP + sub * 8];
      const float4 vb = *(const float4*)&sm[SM_VP + sub * 8 + 4];
      #pragma unroll
      for (int bb = 0; bb < 2; ++bb) {
        const float4 qa = *(const float4*)&sm[SM_Q + bb * 128 + sub * 8];
        const float4 qb = *(const float4*)&sm[SM_Q + bb * 128 + sub * 8 + 4];
        #pragma unroll
        for (int it = 0; it < 4; ++it) {
          const int l = it * 32 + wv * 4 + rr;
          const float* rp = ref_p + ((size_t)l * kB + b0 + bb) * kD + sub * 8;
          const float4 ra = *(const float4*)rp;
          const float4 rb = *(const float4*)(rp + 4);
          float s;
          s  = va.x * tanh_fast(ra.x + qa.x);
          s += va.y * tanh_fast(ra.y + qa.y);
          s += va.z * tanh_fast(ra.z + qa.z);
          s += va.w * tanh_fast(ra.w + qa.w);
          s += vb.x * tanh_fast(rb.x + qb.x);
          s += vb.y * tanh_fast(rb.y + qb.y);
          s += vb.z * tanh_fast(rb.z + qb.z);
          s += vb.w * tanh_fast(rb.w + qb.w);
          s += __shfl_xor(s, 1); s += __shfl_xor(s, 2);
          s += __shfl_xor(s, 4); s += __shfl_xor(s, 8);
          if (sub == 0) {
            float uu = 10.f * tanh_fast(s);
            if (step > 0 && sm[SM_MASK + bb * 128 + l] != 0.f) uu = -INFINITY;
            sm[SM_U + bb * 128 + l] = uu;
          }
        }
      }
    }
    __syncthreads();
    // ---- Phase A7: pointer softmax + first-index argmax ----
    if (t < 128) {
      const int bb = t >> 6, lane = t & 63;
      const float v0 = sm[SM_U + bb * 128 + lane], v1 = sm[SM_U + bb * 128 + 64 + lane];
      float m = fmaxf(v0, v1);
      #pragma unroll
      for (int off = 1; off < 64; off <<= 1) m = fmaxf(m, __shfl_xor(m, off, 64));
      const float e0 = __expf(v0 - m), e1 = __expf(v1 - m);
      float ssum = e0 + e1;
      #pragma unroll
      for (int off = 1; off < 64; off <<= 1) ssum += __shfl_xor(ssum, off, 64);
      const float inv = __fdividef(1.0f, ssum);
      sm[SM_P + bb * 128 + lane]      = e0 * inv;
      sm[SM_P + bb * 128 + 64 + lane] = e1 * inv;
      float av; int ai;
      if (v0 >= v1) { av = v0; ai = lane; } else { av = v1; ai = lane + 64; }
      #pragma unroll
      for (int off = 1; off < 64; off <<= 1) {
        const float ov = __shfl_xor(av, off, 64);
        const int   oi = __shfl_xor(ai, off, 64);
        if (ov > av || (ov == av && oi < ai)) { av = ov; ai = oi; }
      }
      if (lane == 0) {
        s_idx[bb] = ai;
        out[OUT_IDX_OFF + (size_t)step * kB + b0 + bb] = (float)ai;
      }
    }
    __syncthreads();
    // ---- Phase A8: write probs row; gather next decoder input ----
    if (t < 256) {
      const int bb = t >> 7, d = t & 127, b = b0 + bb;
      out[((size_t)step * kB + b) * kL + d] = sm[SM_P + bb * 128 + d];
      const int idx = s_idx[bb];
      sm[SM_XH + d * 2 + bb] = emb[((size_t)idx * kB + b) * kD + d];
    }
    __syncthreads();
  }
}

extern "C" void kernel_launch(void* const* d_in, const int* in_sizes, int n_in,
                              void* d_out, int out_size, void* d_ws, size_t ws_size,
                              hipStream_t stream) {
  (void)in_sizes; (void)n_in; (void)out_size; (void)ws_size;
  const float* dec0 = (const float*)d_in[0];
  const float* emb  = (const float*)d_in[1];
  const float* h0   = (const float*)d_in[2];
  const float* c0   = (const float*)d_in[3];
  const float* enc  = (const float*)d_in[4];
  const float* w_ih = (const float*)d_in[5];
  const float* w_hh = (const float*)d_in[6];
  const float* b_ih = (const float*)d_in[7];
  const float* b_hh = (const float*)d_in[8];
  const float* wq_p = (const float*)d_in[9];
  const float* bq_p = (const float*)d_in[10];
  const float* wr_p = (const float*)d_in[11];
  const float* br_p = (const float*)d_in[12];
  const float* v_p  = (const float*)d_in[13];
  const float* wq_g = (const float*)d_in[14];
  const float* bq_g = (const float*)d_in[15];
  const float* wr_g = (const float*)d_in[16];
  const float* br_g = (const float*)d_in[17];
  const float* v_g  = (const float*)d_in[18];
  float* ws  = (float*)d_ws;
  float* out = (float*)d_out;

  prep_weights<<<dim3(64), dim3(256), 0, stream>>>(
      w_ih, w_hh, b_ih, b_hh, wq_p, wq_g, wr_p, wr_g, ws);
  prep_refs<<<dim3(1024), dim3(256), (32768 + 256) * 4, stream>>>(
      enc, br_p, br_g, ws);
  decode_main<<<dim3(256), dim3(512), SM_TOTAL * 4, stream>>>(
      dec0, emb, h0, c0, enc, w_hh, bq_p, v_p, bq_g, v_g, ws, out);
}

// Round 3
// 5892.125 us; speedup vs baseline: 1.5680x; 1.5680x over previous
//
#include <hip/hip_runtime.h>
#include <math.h>

namespace {

constexpr int kB = 512;
constexpr int kL = 128;
constexpr int kD = 128;
constexpr int kSteps = 126;   // L - 2

// ---- workspace layout (float offsets) ----
constexpr size_t OFF_W2IH = 0;                       // [64][512][2] w_ih pairs
constexpr size_t OFF_W2HH = 65536;                   // [64][512][2] w_hh pairs
constexpr size_t OFF_BIAS = 131072;                  // [512] b_ih + b_hh
constexpr size_t OFF_WQTG = 131584;                  // [128][128] wq_g^T
constexpr size_t OFF_WQTP = 147968;                  // wq_p^T
constexpr size_t OFF_WRTG = 164352;                  // wr_g^T
constexpr size_t OFF_WRTP = 180736;                  // wr_p^T
constexpr size_t OFF_REFG = 197120;                  // [L][B][D]
constexpr size_t OFF_REFP = OFF_REFG + (size_t)kL * kB * kD;

constexpr size_t OUT_IDX_OFF = (size_t)kSteps * kB * kL;  // probs first, then idx

// ---- dynamic LDS layout for decode_main (float offsets) ----
constexpr int SM_WQTG = 0;       // 16384 (pinned wq_g^T)
constexpr int SM_WQTP = 16384;   // 16384 (pinned wq_p^T)
constexpr int SM_XH   = 32768;   // [256][2]  k-major, bb inner (x in k<128, h in k>=128)
constexpr int SM_C    = 33280;   // [2][128]
constexpr int SM_GATES= 33536;   // [2][512]
constexpr int SM_RED  = 34560;   // [1024] reduction scratch
constexpr int SM_Q    = 35584;   // [2][128]
constexpr int SM_U    = 35840;   // [2][128]
constexpr int SM_P    = 36096;   // [2][128]
constexpr int SM_GV   = 36352;   // [128][2] interleaved glimpse vector
constexpr int SM_MASK = 36608;   // [2][128]
constexpr int SM_VG   = 36864;   // [128]
constexpr int SM_VP   = 36992;
constexpr int SM_BQG  = 37120;
constexpr int SM_BQP  = 37248;
constexpr int SM_IDX  = 37376;   // 2 ints
constexpr int SM_TOTAL= 37380;   // 149.5 KB

// fast transcendentals: v_exp_f32-based, ~2 ulp, branch-free, inf-safe
__device__ __forceinline__ float tanh_fast(float x) {
  return 1.0f - __fdividef(2.0f, __expf(2.0f * x) + 1.0f);
}
__device__ __forceinline__ float sig_fast(float x) {
  return __fdividef(1.0f, 1.0f + __expf(-x));
}

} // namespace

// ---------- one-time: transposed weights + fused bias ----------
extern "C" __global__ void prep_weights(
    const float* __restrict__ w_ih, const float* __restrict__ w_hh,
    const float* __restrict__ b_ih, const float* __restrict__ b_hh,
    const float* __restrict__ wq_p, const float* __restrict__ wq_g,
    const float* __restrict__ wr_p, const float* __restrict__ wr_g,
    float* __restrict__ ws) {
  const int tid = blockIdx.x * blockDim.x + threadIdx.x;
  const int nth = gridDim.x * blockDim.x;
  for (int i = tid; i < 64 * 512 * 2; i += nth) {
    const int k2 = i >> 10, rem = i & 1023, g = rem >> 1, half = rem & 1;
    const int k = k2 * 2 + half;
    ws[OFF_W2IH + i] = w_ih[g * 128 + k];
    ws[OFF_W2HH + i] = w_hh[g * 128 + k];
  }
  for (int i = tid; i < 512; i += nth) ws[OFF_BIAS + i] = b_ih[i] + b_hh[i];
  for (int i = tid; i < 128 * 128; i += nth) {
    const int k = i >> 7, j = i & 127;
    ws[OFF_WQTG + i] = wq_g[j * 128 + k];
    ws[OFF_WQTP + i] = wq_p[j * 128 + k];
    ws[OFF_WRTG + i] = wr_g[j * 128 + k];
    ws[OFF_WRTP + i] = wr_p[j * 128 + k];
  }
}

// ---------- one-time: ref_p/ref_g = enc @ wr^T + br (1x1 conv hoisted) ----------
extern "C" __global__ __launch_bounds__(256) void prep_refs(
    const float* __restrict__ enc,
    const float* __restrict__ br_p, const float* __restrict__ br_g,
    float* __restrict__ ws) {
  extern __shared__ float lds[];
  float* s_wrTg = lds;             // 16384
  float* s_wrTp = lds + 16384;     // 16384
  float* s_enc  = lds + 32768;     // [2][128]
  float* ref_g = ws + OFF_REFG;
  float* ref_p = ws + OFF_REFP;
  const int t = threadIdx.x;
  for (int i = t; i < 16384; i += 256) {
    s_wrTg[i] = ws[OFF_WRTG + i];
    s_wrTp[i] = ws[OFF_WRTP + i];
  }
  __syncthreads();
  const int half = t >> 7, j = t & 127;
  const float brg = br_g[j], brp = br_p[j];
  const size_t base = (size_t)blockIdx.x * 64;
  for (int rr = 0; rr < 64; rr += 2) {
    const size_t rid = base + rr + half;   // rid = l*B + b
    s_enc[half * 128 + j] = enc[rid * 128 + j];
    __syncthreads();
    float ag = brg, ap = brp;
    #pragma unroll 8
    for (int k = 0; k < 128; ++k) {
      const float e = s_enc[half * 128 + k];
      ag += e * s_wrTg[k * 128 + j];
      ap += e * s_wrTp[k * 128 + j];
    }
    ref_g[rid * 128 + j] = ag;
    ref_p[rid * 128 + j] = ap;
    __syncthreads();
  }
}

// ---------- persistent decode: one block per 2 batch elements ----------
extern "C" __global__ __launch_bounds__(512) void decode_main(
    const float* __restrict__ dec0, const float* __restrict__ emb,
    const float* __restrict__ h0,   const float* __restrict__ c0,
    const float* __restrict__ enc,
    const float* __restrict__ bq_p, const float* __restrict__ v_p,
    const float* __restrict__ bq_g, const float* __restrict__ v_g,
    const float* __restrict__ ws, float* __restrict__ out) {
  extern __shared__ float sm[];
  int* s_idx = (int*)(sm + SM_IDX);
  const float* W2IH = ws + OFF_W2IH;
  const float* W2HH = ws + OFF_W2HH;

  const int t  = threadIdx.x;
  const int b0 = blockIdx.x * 2;
  const int lane = t & 63, wv = t >> 6;
  const int sub = lane & 15, rr = lane >> 4;

  // ---- register-pinned ref_g / ref_p slices (step-invariant!) ----
  // thread (wv,rr,sub) owns rows l = it*32+wv*4+rr (it=0..3, bb=0..1), dims sub*8..sub*8+7
  float rg[64], rp[64];
  #pragma unroll
  for (int bb = 0; bb < 2; ++bb) {
    #pragma unroll
    for (int it = 0; it < 4; ++it) {
      const int l = it * 32 + wv * 4 + rr;
      const size_t off = ((size_t)l * kB + b0 + bb) * kD + sub * 8;
      *(float4*)&rg[(bb * 4 + it) * 8]     = *(const float4*)(ws + OFF_REFG + off);
      *(float4*)&rg[(bb * 4 + it) * 8 + 4] = *(const float4*)(ws + OFF_REFG + off + 4);
      *(float4*)&rp[(bb * 4 + it) * 8]     = *(const float4*)(ws + OFF_REFP + off);
      *(float4*)&rp[(bb * 4 + it) * 8 + 4] = *(const float4*)(ws + OFF_REFP + off + 4);
    }
  }

  const float bias_g = ws[OFF_BIAS + t];

  // one-time LDS fills: pinned wq tables + state
  for (int i = t; i < 16384; i += 512) {
    sm[SM_WQTG + i] = ws[OFF_WQTG + i];
    sm[SM_WQTP + i] = ws[OFF_WQTP + i];
  }
  if (t < 128) {
    sm[SM_VG  + t] = v_g[t];
    sm[SM_VP  + t] = v_p[t];
    sm[SM_BQG + t] = bq_g[t];
    sm[SM_BQP + t] = bq_p[t];
  }
  if (t < 256) {
    const int bb = t >> 7, d = t & 127, b = b0 + bb;
    sm[SM_XH + d * 2 + bb]         = dec0[b * 128 + d];   // x part
    sm[SM_XH + (128 + d) * 2 + bb] = h0[b * 128 + d];     // h part
    sm[SM_C + bb * 128 + d]        = c0[b * 128 + d];
    sm[SM_MASK + bb * 128 + d]     = (d < 2) ? 1.f : 0.f; // indices 0,1 pre-visited
  }
  __syncthreads();

  for (int step = 0; step < kSteps; ++step) {
    // ---- Phase L1: gates[t] for both batches; w_ih + w_hh streamed from L2 ----
    {
      float a0 = bias_g, a1 = bias_g;
      const float* wpi = W2IH + 2 * t;
      const float* wph = W2HH + 2 * t;
      #pragma unroll 8
      for (int k2 = 0; k2 < 64; ++k2) {
        const float4 xh = *(const float4*)&sm[SM_XH + k2 * 4];  // x[2k2],x[2k2+1] (b0,b1)
        const float2 w  = *(const float2*)(wpi + (size_t)k2 * 1024);
        a0 += xh.x * w.x + xh.z * w.y;
        a1 += xh.y * w.x + xh.w * w.y;
      }
      #pragma unroll 8
      for (int k2 = 0; k2 < 64; ++k2) {
        const float4 hh = *(const float4*)&sm[SM_XH + 256 + k2 * 4];
        const float2 w  = *(const float2*)(wph + (size_t)k2 * 1024);
        a0 += hh.x * w.x + hh.z * w.y;
        a1 += hh.y * w.x + hh.w * w.y;
      }
      sm[SM_GATES + t]       = a0;
      sm[SM_GATES + 512 + t] = a1;
    }
    __syncthreads();
    // ---- Phase L2: LSTM cell elementwise; mask update (use_prev only) ----
    if (t < 256) {
      const int bb = t >> 7, d = t & 127;
      const float gi = sm[SM_GATES + bb * 512 + d];
      const float gf = sm[SM_GATES + bb * 512 + 128 + d];
      const float gg = sm[SM_GATES + bb * 512 + 256 + d];
      const float go = sm[SM_GATES + bb * 512 + 384 + d];
      const float cc = sig_fast(gf) * sm[SM_C + bb * 128 + d] + sig_fast(gi) * tanh_fast(gg);
      const float hh = sig_fast(go) * tanh_fast(cc);
      sm[SM_C + bb * 128 + d] = cc;
      sm[SM_XH + (128 + d) * 2 + bb] = hh;
    }
    if (step > 0 && t < 2) sm[SM_MASK + t * 128 + s_idx[t]] = 1.f;
    __syncthreads();
    // ---- Phase A1: q_g = h @ wq_g^T + bq_g  (wq_g^T pinned in LDS) ----
    {
      const int kq = t >> 7, j = t & 127;
      float acc0 = 0.f, acc1 = 0.f;
      #pragma unroll 8
      for (int kk = 0; kk < 32; ++kk) {
        const int k = kq * 32 + kk;
        const float2 h2 = *(const float2*)&sm[SM_XH + (128 + k) * 2];  // broadcast
        const float w = sm[SM_WQTG + k * 128 + j];
        acc0 += h2.x * w; acc1 += h2.y * w;
      }
      sm[SM_RED + kq * 256 + j]       = acc0;
      sm[SM_RED + kq * 256 + 128 + j] = acc1;
    }
    __syncthreads();
    if (t < 256) {
      const int bb = t >> 7, j = t & 127;
      sm[SM_Q + bb * 128 + j] = sm[SM_BQG + j]
          + sm[SM_RED + bb * 128 + j]       + sm[SM_RED + 256 + bb * 128 + j]
          + sm[SM_RED + 512 + bb * 128 + j] + sm[SM_RED + 768 + bb * 128 + j];
    }
    __syncthreads();
    // ---- Phase A2: glimpse scores u_g[l] = v_g . tanh(ref_g + q_g), ref_g in regs ----
    {
      const float4 va = *(const float4*)&sm[SM_VG + sub * 8];
      const float4 vb = *(const float4*)&sm[SM_VG + sub * 8 + 4];
      #pragma unroll
      for (int bb = 0; bb < 2; ++bb) {
        const float4 qa = *(const float4*)&sm[SM_Q + bb * 128 + sub * 8];
        const float4 qb = *(const float4*)&sm[SM_Q + bb * 128 + sub * 8 + 4];
        #pragma unroll
        for (int it = 0; it < 4; ++it) {
          const int l = it * 32 + wv * 4 + rr;
          const int rbase = (bb * 4 + it) * 8;
          float s;
          s  = va.x * tanh_fast(rg[rbase + 0] + qa.x);
          s += va.y * tanh_fast(rg[rbase + 1] + qa.y);
          s += va.z * tanh_fast(rg[rbase + 2] + qa.z);
          s += va.w * tanh_fast(rg[rbase + 3] + qa.w);
          s += vb.x * tanh_fast(rg[rbase + 4] + qb.x);
          s += vb.y * tanh_fast(rg[rbase + 5] + qb.y);
          s += vb.z * tanh_fast(rg[rbase + 6] + qb.z);
          s += vb.w * tanh_fast(rg[rbase + 7] + qb.w);
          s += __shfl_xor(s, 1); s += __shfl_xor(s, 2);
          s += __shfl_xor(s, 4); s += __shfl_xor(s, 8);
          if (sub == 0) {
            if (step > 0 && sm[SM_MASK + bb * 128 + l] != 0.f) s = -INFINITY;
            sm[SM_U + bb * 128 + l] = s;
          }
        }
      }
    }
    __syncthreads();
    // ---- Phase A3: glimpse softmax (wave 0 -> b0, wave 1 -> b1) ----
    if (t < 128) {
      const int bb = t >> 6, ln = t & 63;
      const float v0 = sm[SM_U + bb * 128 + ln], v1 = sm[SM_U + bb * 128 + 64 + ln];
      float m = fmaxf(v0, v1);
      #pragma unroll
      for (int off = 1; off < 64; off <<= 1) m = fmaxf(m, __shfl_xor(m, off, 64));
      const float e0 = __expf(v0 - m), e1 = __expf(v1 - m);
      float ssum = e0 + e1;
      #pragma unroll
      for (int off = 1; off < 64; off <<= 1) ssum += __shfl_xor(ssum, off, 64);
      const float inv = __fdividef(1.0f, ssum);
      sm[SM_P + bb * 128 + ln]      = e0 * inv;
      sm[SM_P + bb * 128 + 64 + ln] = e1 * inv;
    }
    __syncthreads();
    // ---- Phase A4: glimpse readout g = p @ enc (enc streamed, L3-resident) ----
    {
      const int lh = t >> 8, bb = (t >> 7) & 1, d = t & 127;
      float acc = 0.f;
      #pragma unroll 8
      for (int ll = 0; ll < 64; ++ll) {
        const int l = lh * 64 + ll;
        acc += sm[SM_P + bb * 128 + l] * enc[((size_t)l * kB + b0 + bb) * kD + d];
      }
      sm[SM_RED + (lh * 2 + bb) * 128 + d] = acc;
    }
    __syncthreads();
    if (t < 256) {
      const int bb = t >> 7, d = t & 127;
      sm[SM_GV + d * 2 + bb] = sm[SM_RED + bb * 128 + d] + sm[SM_RED + (2 + bb) * 128 + d];
    }
    __syncthreads();
    // ---- Phase A5: q_p = g @ wq_p^T + bq_p  (wq_p^T pinned in LDS) ----
    {
      const int kq = t >> 7, j = t & 127;
      float acc0 = 0.f, acc1 = 0.f;
      #pragma unroll 8
      for (int kk = 0; kk < 32; ++kk) {
        const int k = kq * 32 + kk;
        const float2 g2 = *(const float2*)&sm[SM_GV + k * 2];  // broadcast
        const float w = sm[SM_WQTP + k * 128 + j];
        acc0 += g2.x * w; acc1 += g2.y * w;
      }
      sm[SM_RED + kq * 256 + j]       = acc0;
      sm[SM_RED + kq * 256 + 128 + j] = acc1;
    }
    __syncthreads();
    if (t < 256) {
      const int bb = t >> 7, j = t & 127;
      sm[SM_Q + bb * 128 + j] = sm[SM_BQP + j]
          + sm[SM_RED + bb * 128 + j]       + sm[SM_RED + 256 + bb * 128 + j]
          + sm[SM_RED + 512 + bb * 128 + j] + sm[SM_RED + 768 + bb * 128 + j];
    }
    __syncthreads();
    // ---- Phase A6: pointer scores, clipped 10*tanh(u), masked; ref_p in regs ----
    {
      const float4 va = *(const float4*)&sm[SM_VP + sub * 8];
      const float4 vb = *(const float4*)&sm[SM_VP + sub * 8 + 4];
      #pragma unroll
      for (int bb = 0; bb < 2; ++bb) {
        const float4 qa = *(const float4*)&sm[SM_Q + bb * 128 + sub * 8];
        const float4 qb = *(const float4*)&sm[SM_Q + bb * 128 + sub * 8 + 4];
        #pragma unroll
        for (int it = 0; it < 4; ++it) {
          const int l = it * 32 + wv * 4 + rr;
          const int rbase = (bb * 4 + it) * 8;
          float s;
          s  = va.x * tanh_fast(rp[rbase + 0] + qa.x);
          s += va.y * tanh_fast(rp[rbase + 1] + qa.y);
          s += va.z * tanh_fast(rp[rbase + 2] + qa.z);
          s += va.w * tanh_fast(rp[rbase + 3] + qa.w);
          s += vb.x * tanh_fast(rp[rbase + 4] + qb.x);
          s += vb.y * tanh_fast(rp[rbase + 5] + qb.y);
          s += vb.z * tanh_fast(rp[rbase + 6] + qb.z);
          s += vb.w * tanh_fast(rp[rbase + 7] + qb.w);
          s += __shfl_xor(s, 1); s += __shfl_xor(s, 2);
          s += __shfl_xor(s, 4); s += __shfl_xor(s, 8);
          if (sub == 0) {
            float uu = 10.f * tanh_fast(s);
            if (step > 0 && sm[SM_MASK + bb * 128 + l] != 0.f) uu = -INFINITY;
            sm[SM_U + bb * 128 + l] = uu;
          }
        }
      }
    }
    __syncthreads();
    // ---- Phase A7: pointer softmax + first-index argmax ----
    if (t < 128) {
      const int bb = t >> 6, ln = t & 63;
      const float v0 = sm[SM_U + bb * 128 + ln], v1 = sm[SM_U + bb * 128 + 64 + ln];
      float m = fmaxf(v0, v1);
      #pragma unroll
      for (int off = 1; off < 64; off <<= 1) m = fmaxf(m, __shfl_xor(m, off, 64));
      const float e0 = __expf(v0 - m), e1 = __expf(v1 - m);
      float ssum = e0 + e1;
      #pragma unroll
      for (int off = 1; off < 64; off <<= 1) ssum += __shfl_xor(ssum, off, 64);
      const float inv = __fdividef(1.0f, ssum);
      sm[SM_P + bb * 128 + ln]      = e0 * inv;
      sm[SM_P + bb * 128 + 64 + ln] = e1 * inv;
      float av; int ai;
      if (v0 >= v1) { av = v0; ai = ln; } else { av = v1; ai = ln + 64; }
      #pragma unroll
      for (int off = 1; off < 64; off <<= 1) {
        const float ov = __shfl_xor(av, off, 64);
        const int   oi = __shfl_xor(ai, off, 64);
        if (ov > av || (ov == av && oi < ai)) { av = ov; ai = oi; }
      }
      if (ln == 0) {
        s_idx[bb] = ai;
        out[OUT_IDX_OFF + (size_t)step * kB + b0 + bb] = (float)ai;
      }
    }
    __syncthreads();
    // ---- Phase A8: write probs row; gather next decoder input ----
    if (t < 256) {
      const int bb = t >> 7, d = t & 127, b = b0 + bb;
      out[((size_t)step * kB + b) * kL + d] = sm[SM_P + bb * 128 + d];
      const int idx = s_idx[bb];
      sm[SM_XH + d * 2 + bb] = emb[((size_t)idx * kB + b) * kD + d];
    }
    __syncthreads();
  }
}

extern "C" void kernel_launch(void* const* d_in, const int* in_sizes, int n_in,
                              void* d_out, int out_size, void* d_ws, size_t ws_size,
                              hipStream_t stream) {
  (void)in_sizes; (void)n_in; (void)out_size; (void)ws_size;
  const float* dec0 = (const float*)d_in[0];
  const float* emb  = (const float*)d_in[1];
  const float* h0   = (const float*)d_in[2];
  const float* c0   = (const float*)d_in[3];
  const float* enc  = (const float*)d_in[4];
  const float* w_ih = (const float*)d_in[5];
  const float* w_hh = (const float*)d_in[6];
  const float* b_ih = (const float*)d_in[7];
  const float* b_hh = (const float*)d_in[8];
  const float* wq_p = (const float*)d_in[9];
  const float* bq_p = (const float*)d_in[10];
  const float* wr_p = (const float*)d_in[11];
  const float* br_p = (const float*)d_in[12];
  const float* v_p  = (const float*)d_in[13];
  const float* wq_g = (const float*)d_in[14];
  const float* bq_g = (const float*)d_in[15];
  const float* wr_g = (const float*)d_in[16];
  const float* br_g = (const float*)d_in[17];
  const float* v_g  = (const float*)d_in[18];
  float* ws  = (float*)d_ws;
  float* out = (float*)d_out;

  prep_weights<<<dim3(64), dim3(256), 0, stream>>>(
      w_ih, w_hh, b_ih, b_hh, wq_p, wq_g, wr_p, wr_g, ws);
  prep_refs<<<dim3(1024), dim3(256), (32768 + 256) * 4, stream>>>(
      enc, br_p, br_g, ws);
  decode_main<<<dim3(256), dim3(512), SM_TOTAL * 4, stream>>>(
      dec0, emb, h0, c0, enc, bq_p, v_p, bq_g, v_g, ws, out);
}

// Round 4
// 4616.410 us; speedup vs baseline: 2.0013x; 1.2763x over previous
//
#include <hip/hip_runtime.h>
#include <math.h>

namespace {

constexpr int kB = 512;
constexpr int kL = 128;
constexpr int kD = 128;
constexpr int kSteps = 126;   // L - 2

// ---- workspace layout (float offsets) ----
constexpr size_t OFF_WL   = 0;                       // [256][512] k-major: k<128 w_ih, else w_hh
constexpr size_t OFF_BIAS = 131072;                  // [512] b_ih + b_hh
constexpr size_t OFF_WQLG = 131584;                  // [16][256][4] lane-matched wq_g (see prep)
constexpr size_t OFF_WQLP = 147968;                  // same for wq_p
constexpr size_t OFF_WRTG = 164352;                  // [128][128] wr_g^T (for prep_refs)
constexpr size_t OFF_WRTP = 180736;                  // wr_p^T
constexpr size_t OFF_REFG = 197120;                  // [L][B][D]
constexpr size_t OFF_REFP = OFF_REFG + (size_t)kL * kB * kD;

constexpr size_t OUT_IDX_OFF = (size_t)kSteps * kB * kL;  // probs first, then idx

// ---- static LDS layout (float offsets), ~7.7 KB per block ----
constexpr int SM_XH  = 0;     // [256] x in 0..127, h in 128..255
constexpr int SM_C   = 256;   // [128]
constexpr int SM_G   = 384;   // [512] gates
constexpr int SM_RED = 896;   // [256] A4 partials (lh-major)
constexpr int SM_Q   = 1152;  // [128]
constexpr int SM_U   = 1280;  // [128]
constexpr int SM_P   = 1408;  // [128]
constexpr int SM_M   = 1536;  // [128] mask
constexpr int SM_VG  = 1664;  // [128]
constexpr int SM_VP  = 1792;  // [128]
constexpr int SM_IDX = 1920;  // int
constexpr int SM_TOTAL = 1924;

// fast transcendentals: v_exp_f32-based, ~2 ulp, branch-free, inf-safe
__device__ __forceinline__ float tanh_fast(float x) {
  return 1.0f - __fdividef(2.0f, __expf(2.0f * x) + 1.0f);
}
__device__ __forceinline__ float sig_fast(float x) {
  return __fdividef(1.0f, 1.0f + __expf(-x));
}

} // namespace

// ---------- one-time: weight relayouts + fused bias ----------
extern "C" __global__ void prep_weights(
    const float* __restrict__ w_ih, const float* __restrict__ w_hh,
    const float* __restrict__ b_ih, const float* __restrict__ b_hh,
    const float* __restrict__ wq_p, const float* __restrict__ wq_g,
    const float* __restrict__ wr_p, const float* __restrict__ wr_g,
    float* __restrict__ ws) {
  const int tid = blockIdx.x * blockDim.x + threadIdx.x;
  const int nth = gridDim.x * blockDim.x;
  // WL[k][g], k-major
  for (int i = tid; i < 256 * 512; i += nth) {
    const int k = i >> 9, g = i & 511;
    ws[OFF_WL + i] = (k < 128) ? w_ih[g * 128 + k] : w_hh[g * 128 + (k - 128)];
  }
  for (int i = tid; i < 512; i += nth) ws[OFF_BIAS + i] = b_ih[i] + b_hh[i];
  // WQL[kk4][t=(j*2+kq)][e]: lane t at iter kk4 reads float4 = wq[j][kq*64 + kk4*4 + e]
  for (int i = tid; i < 16384; i += nth) {
    const int e = i & 3, rest = i >> 2;
    const int kq = rest & 1, j = (rest >> 1) & 127, kk4 = rest >> 8;
    const int k = kq * 64 + kk4 * 4 + e;
    ws[OFF_WQLG + i] = wq_g[j * 128 + k];
    ws[OFF_WQLP + i] = wq_p[j * 128 + k];
  }
  for (int i = tid; i < 128 * 128; i += nth) {
    const int k = i >> 7, j = i & 127;
    ws[OFF_WRTG + i] = wr_g[j * 128 + k];
    ws[OFF_WRTP + i] = wr_p[j * 128 + k];
  }
}

// ---------- one-time: ref_p/ref_g = enc @ wr^T + br (1x1 conv hoisted) ----------
extern "C" __global__ __launch_bounds__(256) void prep_refs(
    const float* __restrict__ enc,
    const float* __restrict__ br_p, const float* __restrict__ br_g,
    float* __restrict__ ws) {
  extern __shared__ float lds[];
  float* s_wrTg = lds;             // 16384
  float* s_wrTp = lds + 16384;     // 16384
  float* s_enc  = lds + 32768;     // [2][128]
  float* ref_g = ws + OFF_REFG;
  float* ref_p = ws + OFF_REFP;
  const int t = threadIdx.x;
  for (int i = t; i < 16384; i += 256) {
    s_wrTg[i] = ws[OFF_WRTG + i];
    s_wrTp[i] = ws[OFF_WRTP + i];
  }
  __syncthreads();
  const int half = t >> 7, j = t & 127;
  const float brg = br_g[j], brp = br_p[j];
  const size_t base = (size_t)blockIdx.x * 64;
  for (int rr = 0; rr < 64; rr += 2) {
    const size_t rid = base + rr + half;   // rid = l*B + b
    s_enc[half * 128 + j] = enc[rid * 128 + j];
    __syncthreads();
    float ag = brg, ap = brp;
    #pragma unroll 8
    for (int k = 0; k < 128; ++k) {
      const float e = s_enc[half * 128 + k];
      ag += e * s_wrTg[k * 128 + j];
      ap += e * s_wrTp[k * 128 + j];
    }
    ref_g[rid * 128 + j] = ag;
    ref_p[rid * 128 + j] = ap;
    __syncthreads();
  }
}

// ---------- persistent decode: one block per batch element, 2 blocks/CU ----------
extern "C" __global__ __launch_bounds__(256, 2) void decode_main(
    const float* __restrict__ dec0, const float* __restrict__ emb,
    const float* __restrict__ h0,   const float* __restrict__ c0,
    const float* __restrict__ enc,
    const float* __restrict__ bq_p, const float* __restrict__ v_p,
    const float* __restrict__ bq_g, const float* __restrict__ v_g,
    const float* __restrict__ ws, float* __restrict__ out) {
  __shared__ float sm[SM_TOTAL];
  int* s_idx = (int*)(sm + SM_IDX);

  const int t = threadIdx.x;
  const int b = blockIdx.x;
  const int wv = t >> 6, lane = t & 63;
  const int sub = lane & 15, rr = lane >> 4;
  const int j = t >> 1, kq = t & 1;      // A1/A5 mapping
  const int lh = t >> 7, dd = t & 127;   // A4 / half mappings

  // ---- register pins (step-invariant) ----
  // rg/rp: thread (wv,rr,sub) owns rows l = it*16+wv*4+rr (it=0..7), dims sub*8..+7
  float rg[64], rp[64];
  #pragma unroll
  for (int it = 0; it < 8; ++it) {
    const int l = it * 16 + wv * 4 + rr;
    const size_t off = ((size_t)l * kB + b) * kD + sub * 8;
    *(float4*)&rg[it * 8]     = *(const float4*)(ws + OFF_REFG + off);
    *(float4*)&rg[it * 8 + 4] = *(const float4*)(ws + OFF_REFG + off + 4);
    *(float4*)&rp[it * 8]     = *(const float4*)(ws + OFF_REFP + off);
    *(float4*)&rp[it * 8 + 4] = *(const float4*)(ws + OFF_REFP + off + 4);
  }
  // enc pins: thread (lh,dd) owns enc[lh*64+ll][b][dd], ll=0..63
  float en[64];
  #pragma unroll 8
  for (int ll = 0; ll < 64; ++ll) {
    en[ll] = enc[((size_t)(lh * 64 + ll) * kB + b) * kD + dd];
  }

  const float bias0 = ws[OFF_BIAS + 2 * t];
  const float bias1 = ws[OFF_BIAS + 2 * t + 1];
  const float bqg = bq_g[j], bqp = bq_p[j];

  if (t < 128) {
    sm[SM_XH + t]       = dec0[b * 128 + t];
    sm[SM_XH + 128 + t] = h0[b * 128 + t];
    sm[SM_C + t]        = c0[b * 128 + t];
    sm[SM_M + t]        = (t < 2) ? 1.f : 0.f;
    sm[SM_VG + t]       = v_g[t];
    sm[SM_VP + t]       = v_p[t];
  }
  __syncthreads();

  const float* WL   = ws + OFF_WL + 2 * t;
  const float* WQG  = ws + OFF_WQLG + 4 * t;
  const float* WQP  = ws + OFF_WQLP + 4 * t;

  for (int step = 0; step < kSteps; ++step) {
    // ---- P1: LSTM gates (2t, 2t+1); W streamed from L2, xh broadcast from LDS ----
    {
      float a0 = bias0, a1 = bias1;
      #pragma unroll 8
      for (int k4 = 0; k4 < 64; ++k4) {
        const float4 xh = *(const float4*)&sm[SM_XH + k4 * 4];
        const float2 w0 = *(const float2*)(WL + (size_t)(k4 * 4 + 0) * 512);
        const float2 w1 = *(const float2*)(WL + (size_t)(k4 * 4 + 1) * 512);
        const float2 w2 = *(const float2*)(WL + (size_t)(k4 * 4 + 2) * 512);
        const float2 w3 = *(const float2*)(WL + (size_t)(k4 * 4 + 3) * 512);
        a0 += xh.x * w0.x + xh.y * w1.x + xh.z * w2.x + xh.w * w3.x;
        a1 += xh.x * w0.y + xh.y * w1.y + xh.z * w2.y + xh.w * w3.y;
      }
      *(float2*)&sm[SM_G + 2 * t] = make_float2(a0, a1);
    }
    __syncthreads();  // B1
    // ---- P2: LSTM cell (t<128); mask update by t==128 ----
    if (t < 128) {
      const float gi = sm[SM_G + t];
      const float gf = sm[SM_G + 128 + t];
      const float gg = sm[SM_G + 256 + t];
      const float go = sm[SM_G + 384 + t];
      const float cc = sig_fast(gf) * sm[SM_C + t] + sig_fast(gi) * tanh_fast(gg);
      sm[SM_C + t] = cc;
      sm[SM_XH + 128 + t] = sig_fast(go) * tanh_fast(cc);
    } else if (t == 128 && step > 0) {
      sm[SM_M + *s_idx] = 1.f;
    }
    __syncthreads();  // B2
    // ---- P3: q_g[j] = h . wq_g[j] (k split across lane pairs, shfl-combined) ----
    {
      float acc = 0.f;
      #pragma unroll 4
      for (int kk4 = 0; kk4 < 16; ++kk4) {
        const float4 w  = *(const float4*)(WQG + (size_t)kk4 * 1024);
        const float4 h4 = *(const float4*)&sm[SM_XH + 128 + kq * 64 + kk4 * 4];
        acc += h4.x * w.x + h4.y * w.y + h4.z * w.z + h4.w * w.w;
      }
      acc += __shfl_xor(acc, 1);
      if (!(t & 1)) sm[SM_Q + j] = acc + bqg;
    }
    __syncthreads();  // B3
    // ---- P4: glimpse scores from register-pinned ref_g ----
    {
      const float4 qa = *(const float4*)&sm[SM_Q + sub * 8];
      const float4 qb = *(const float4*)&sm[SM_Q + sub * 8 + 4];
      const float4 va = *(const float4*)&sm[SM_VG + sub * 8];
      const float4 vb = *(const float4*)&sm[SM_VG + sub * 8 + 4];
      #pragma unroll
      for (int it = 0; it < 8; ++it) {
        const int l = it * 16 + wv * 4 + rr;
        const int rb = it * 8;
        float s;
        s  = va.x * tanh_fast(rg[rb + 0] + qa.x);
        s += va.y * tanh_fast(rg[rb + 1] + qa.y);
        s += va.z * tanh_fast(rg[rb + 2] + qa.z);
        s += va.w * tanh_fast(rg[rb + 3] + qa.w);
        s += vb.x * tanh_fast(rg[rb + 4] + qb.x);
        s += vb.y * tanh_fast(rg[rb + 5] + qb.y);
        s += vb.z * tanh_fast(rg[rb + 6] + qb.z);
        s += vb.w * tanh_fast(rg[rb + 7] + qb.w);
        s += __shfl_xor(s, 1); s += __shfl_xor(s, 2);
        s += __shfl_xor(s, 4); s += __shfl_xor(s, 8);
        if (sub == 0) {
          if (step > 0 && sm[SM_M + l] != 0.f) s = -INFINITY;
          sm[SM_U + l] = s;
        }
      }
    }
    __syncthreads();  // B4
    // ---- P5: glimpse softmax (wave 0) ----
    if (t < 64) {
      const float v0 = sm[SM_U + t], v1 = sm[SM_U + 64 + t];
      float m = fmaxf(v0, v1);
      #pragma unroll
      for (int off = 1; off < 64; off <<= 1) m = fmaxf(m, __shfl_xor(m, off, 64));
      const float e0 = __expf(v0 - m), e1 = __expf(v1 - m);
      float ssum = e0 + e1;
      #pragma unroll
      for (int off = 1; off < 64; off <<= 1) ssum += __shfl_xor(ssum, off, 64);
      const float inv = __fdividef(1.0f, ssum);
      sm[SM_P + t]      = e0 * inv;
      sm[SM_P + 64 + t] = e1 * inv;
    }
    __syncthreads();  // B5
    // ---- P6: glimpse readout partials from register-pinned enc ----
    {
      float acc = 0.f;
      #pragma unroll 8
      for (int ll = 0; ll < 64; ++ll) {
        acc += sm[SM_P + lh * 64 + ll] * en[ll];
      }
      sm[SM_RED + t] = acc;   // RED[lh*128 + dd]
    }
    __syncthreads();  // B6
    // ---- P7: q_p[j] = g . wq_p[j], g folded from RED halves ----
    {
      float acc = 0.f;
      #pragma unroll 4
      for (int kk4 = 0; kk4 < 16; ++kk4) {
        const float4 w  = *(const float4*)(WQP + (size_t)kk4 * 1024);
        const float4 r0 = *(const float4*)&sm[SM_RED + kq * 64 + kk4 * 4];
        const float4 r1 = *(const float4*)&sm[SM_RED + 128 + kq * 64 + kk4 * 4];
        acc += (r0.x + r1.x) * w.x + (r0.y + r1.y) * w.y
             + (r0.z + r1.z) * w.z + (r0.w + r1.w) * w.w;
      }
      acc += __shfl_xor(acc, 1);
      if (!(t & 1)) sm[SM_Q + j] = acc + bqp;
    }
    __syncthreads();  // B7
    // ---- P8: pointer scores from register-pinned ref_p; 10*tanh clip; mask ----
    {
      const float4 qa = *(const float4*)&sm[SM_Q + sub * 8];
      const float4 qb = *(const float4*)&sm[SM_Q + sub * 8 + 4];
      const float4 va = *(const float4*)&sm[SM_VP + sub * 8];
      const float4 vb = *(const float4*)&sm[SM_VP + sub * 8 + 4];
      #pragma unroll
      for (int it = 0; it < 8; ++it) {
        const int l = it * 16 + wv * 4 + rr;
        const int rb = it * 8;
        float s;
        s  = va.x * tanh_fast(rp[rb + 0] + qa.x);
        s += va.y * tanh_fast(rp[rb + 1] + qa.y);
        s += va.z * tanh_fast(rp[rb + 2] + qa.z);
        s += va.w * tanh_fast(rp[rb + 3] + qa.w);
        s += vb.x * tanh_fast(rp[rb + 4] + qb.x);
        s += vb.y * tanh_fast(rp[rb + 5] + qb.y);
        s += vb.z * tanh_fast(rp[rb + 6] + qb.z);
        s += vb.w * tanh_fast(rp[rb + 7] + qb.w);
        s += __shfl_xor(s, 1); s += __shfl_xor(s, 2);
        s += __shfl_xor(s, 4); s += __shfl_xor(s, 8);
        if (sub == 0) {
          float uu = 10.f * tanh_fast(s);
          if (step > 0 && sm[SM_M + l] != 0.f) uu = -INFINITY;
          sm[SM_U + l] = uu;
        }
      }
    }
    __syncthreads();  // B8
    // ---- P9: pointer softmax + first-index argmax (wave 0) ----
    if (t < 64) {
      const float v0 = sm[SM_U + t], v1 = sm[SM_U + 64 + t];
      float m = fmaxf(v0, v1);
      #pragma unroll
      for (int off = 1; off < 64; off <<= 1) m = fmaxf(m, __shfl_xor(m, off, 64));
      const float e0 = __expf(v0 - m), e1 = __expf(v1 - m);
      float ssum = e0 + e1;
      #pragma unroll
      for (int off = 1; off < 64; off <<= 1) ssum += __shfl_xor(ssum, off, 64);
      const float inv = __fdividef(1.0f, ssum);
      sm[SM_P + t]      = e0 * inv;
      sm[SM_P + 64 + t] = e1 * inv;
      float av; int ai;
      if (v0 >= v1) { av = v0; ai = t; } else { av = v1; ai = t + 64; }
      #pragma unroll
      for (int off = 1; off < 64; off <<= 1) {
        const float ov = __shfl_xor(av, off, 64);
        const int   oi = __shfl_xor(ai, off, 64);
        if (ov > av || (ov == av && oi < ai)) { av = ov; ai = oi; }
      }
      if (t == 0) {
        *s_idx = ai;
        out[OUT_IDX_OFF + (size_t)step * kB + b] = (float)ai;
      }
    }
    __syncthreads();  // B9
    // ---- P10: write probs; gather next decoder input ----
    if (t < 128) {
      out[((size_t)step * kB + b) * kL + t] = sm[SM_P + t];
    } else {
      const int d = t - 128;
      sm[SM_XH + d] = emb[((size_t)(*s_idx) * kB + b) * kD + d];
    }
    __syncthreads();  // B10
  }
}

extern "C" void kernel_launch(void* const* d_in, const int* in_sizes, int n_in,
                              void* d_out, int out_size, void* d_ws, size_t ws_size,
                              hipStream_t stream) {
  (void)in_sizes; (void)n_in; (void)out_size; (void)ws_size;
  const float* dec0 = (const float*)d_in[0];
  const float* emb  = (const float*)d_in[1];
  const float* h0   = (const float*)d_in[2];
  const float* c0   = (const float*)d_in[3];
  const float* enc  = (const float*)d_in[4];
  const float* w_ih = (const float*)d_in[5];
  const float* w_hh = (const float*)d_in[6];
  const float* b_ih = (const float*)d_in[7];
  const float* b_hh = (const float*)d_in[8];
  const float* wq_p = (const float*)d_in[9];
  const float* bq_p = (const float*)d_in[10];
  const float* wr_p = (const float*)d_in[11];
  const float* br_p = (const float*)d_in[12];
  const float* v_p  = (const float*)d_in[13];
  const float* wq_g = (const float*)d_in[14];
  const float* bq_g = (const float*)d_in[15];
  const float* wr_g = (const float*)d_in[16];
  const float* br_g = (const float*)d_in[17];
  const float* v_g  = (const float*)d_in[18];
  float* ws  = (float*)d_ws;
  float* out = (float*)d_out;

  prep_weights<<<dim3(64), dim3(256), 0, stream>>>(
      w_ih, w_hh, b_ih, b_hh, wq_p, wq_g, wr_p, wr_g, ws);
  prep_refs<<<dim3(1024), dim3(256), (32768 + 256) * 4, stream>>>(
      enc, br_p, br_g, ws);
  decode_main<<<dim3(512), dim3(256), 0, stream>>>(
      dec0, emb, h0, c0, enc, bq_p, v_p, bq_g, v_g, ws, out);
}